// Round 6
// baseline (714.634 us; speedup 1.0000x reference)
//
#include <hip/hip_runtime.h>
#include <hip/hip_bf16.h>
#include <hip/hip_fp16.h>

#define N_NODES 50000
#define N_EDGES 1600000
#define HIDDEN  128
#define EPS_C   0.3f
#define NWORDS  12500      // 50000 nodes, 4 u8 counters per u32 word
#define CHUNK   25000      // edges per histogram block; 64 chunks = 1.6M
#define NCHUNK  64
#define RBLOCKS 49         // reduce blocks: ceil(12500/256)

typedef _Float16 f16x8 __attribute__((ext_vector_type(8)));
typedef float    f32x16 __attribute__((ext_vector_type(16)));

// ---------------- per-chunk LDS histograms (u8-packed), zero global atomics ----------------
// grid 128: blocks 0..63 count rows (deg), 64..127 count cols (cnt)
__global__ __launch_bounds__(256) void k_hist(const int* __restrict__ ei, unsigned int* __restrict__ part) {
    __shared__ unsigned int hist[NWORDS];   // 50 KB
    int b = blockIdx.x;
    int type  = b >> 6;
    int chunk = b & 63;
    const int* src = ei + (size_t)type * N_EDGES + (size_t)chunk * CHUNK;
    for (int i = threadIdx.x; i < NWORDS; i += 256) hist[i] = 0;
    __syncthreads();
    for (int i = threadIdx.x; i < CHUNK; i += 256) {
        int v = src[i];
        atomicAdd(&hist[v >> 2], 1u << ((v & 3) * 8));
    }
    __syncthreads();
    unsigned int* dst = part + ((size_t)type * NCHUNK + chunk) * NWORDS;
    for (int i = threadIdx.x; i < NWORDS; i += 256) dst[i] = hist[i];
}

// ---------------- reduce partials -> nd, cnt, per-(chunk,col) prefix; tail blocks cvt W1 ----------------
__global__ __launch_bounds__(256) void k_reduce(const unsigned int* __restrict__ part,
                                                float* __restrict__ nd, int* __restrict__ cnt,
                                                unsigned short* __restrict__ cntpre,
                                                const float4* __restrict__ wsrc, __half2* __restrict__ wdst) {
    if (blockIdx.x >= RBLOCKS) {
        int i = (blockIdx.x - RBLOCKS) * 256 + threadIdx.x;   // 64 blocks * 256 = 16384 exactly
        float4 v = wsrc[i];
        wdst[2 * i]     = __floats2half2_rn(v.x, v.y);
        wdst[2 * i + 1] = __floats2half2_rn(v.z, v.w);
        return;
    }
    int w = blockIdx.x * 256 + threadIdx.x;
    if (w >= NWORDS) return;
    // deg (rows)
    unsigned int s0 = 0, s1 = 0, s2 = 0, s3 = 0;
    const unsigned int* dp = part + w;
    for (int b = 0; b < NCHUNK; ++b) {
        unsigned int v = dp[(size_t)b * NWORDS];
        s0 += v & 255u; s1 += (v >> 8) & 255u; s2 += (v >> 16) & 255u; s3 += v >> 24;
    }
    nd[4 * w + 0] = rsqrtf(fmaxf((float)s0, 1.f));
    nd[4 * w + 1] = rsqrtf(fmaxf((float)s1, 1.f));
    nd[4 * w + 2] = rsqrtf(fmaxf((float)s2, 1.f));
    nd[4 * w + 3] = rsqrtf(fmaxf((float)s3, 1.f));
    // cnt (cols) + exclusive prefix per chunk
    const unsigned int* cp = part + (size_t)NCHUNK * NWORDS + w;
    unsigned int r0 = 0, r1 = 0, r2 = 0, r3 = 0;
    for (int b = 0; b < NCHUNK; ++b) {
        size_t o = (size_t)b * N_NODES + 4 * w;
        *(ushort4*)&cntpre[o] = make_ushort4((unsigned short)r0, (unsigned short)r1,
                                             (unsigned short)r2, (unsigned short)r3);
        unsigned int v = cp[(size_t)b * NWORDS];
        r0 += v & 255u; r1 += (v >> 8) & 255u; r2 += (v >> 16) & 255u; r3 += v >> 24;
    }
    cnt[4 * w + 0] = (int)r0;
    cnt[4 * w + 1] = (int)r1;
    cnt[4 * w + 2] = (int)r2;
    cnt[4 * w + 3] = (int)r3;
}

// ---------------- single-block exclusive scan: cnt -> colptr ----------------
__global__ __launch_bounds__(1024) void k_scan(const int* __restrict__ cnt, int* __restrict__ colptr) {
    __shared__ int wsum[16];
    int t = threadIdx.x;
    int lane = t & 63, w = t >> 6;
    int base = t * 49;                       // 1024*49 = 50176 >= 50000
    int s = 0;
    for (int i = 0; i < 49; ++i) { int idx = base + i; s += (idx < N_NODES) ? cnt[idx] : 0; }
    int inc = s;
#pragma unroll
    for (int off = 1; off < 64; off <<= 1) { int u = __shfl_up(inc, off, 64); if (lane >= off) inc += u; }
    if (lane == 63) wsum[w] = inc;
    __syncthreads();
    if (w == 0 && lane < 16) {
        int v = wsum[lane];
#pragma unroll
        for (int off = 1; off < 16; off <<= 1) { int u = __shfl_up(v, off, 64); if (lane >= off) v += u; }
        wsum[lane] = v;   // inclusive wave sums
    }
    __syncthreads();
    int run = inc - s + (w > 0 ? wsum[w - 1] : 0);
    for (int i = 0; i < 49; ++i) {
        int idx = base + i;
        if (idx < N_NODES) { colptr[idx] = run; run += cnt[idx]; }
    }
    if (t == 1023) colptr[N_NODES] = run;    // == E
}

// ---------------- scatter via LDS rank, zero global atomics ----------------
__global__ __launch_bounds__(256) void k_scatter2(const int* __restrict__ ei, const int* __restrict__ colptr,
                                                  const unsigned short* __restrict__ cntpre,
                                                  int* __restrict__ csr) {
    __shared__ unsigned int rank[NWORDS];   // 50 KB
    int b = blockIdx.x;
    for (int i = threadIdx.x; i < NWORDS; i += 256) rank[i] = 0;
    __syncthreads();
    const int* rs = ei + (size_t)b * CHUNK;
    const int* cs = ei + N_EDGES + (size_t)b * CHUNK;
    const unsigned short* pre = cntpre + (size_t)b * N_NODES;
    for (int i = threadIdx.x; i < CHUNK; i += 256) {
        int r = rs[i];
        int c = cs[i];
        unsigned int old = atomicAdd(&rank[c >> 2], 1u << ((c & 3) * 8));
        unsigned int lr = (old >> ((c & 3) * 8)) & 255u;
        int pos = colptr[c] + (int)pre[c] + (int)lr;
        csr[pos] = r;
    }
}

// ---------------- GEMM1: hb = relu(x @ W1^T + b1) fp16, MFMA, packed half2 stores ----------------
// block = 4 waves over M=64 x N=128; wave tile = M32 x N64; lane lm owns adjacent cols n0+2lm, n0+2lm+1
__global__ __launch_bounds__(256) void k_gemm1(const float* __restrict__ x, const _Float16* __restrict__ wh,
                                               const float* __restrict__ bias, __half2* __restrict__ hb) {
    int wave = threadIdx.x >> 6;
    int lane = threadIdx.x & 63;
    int mstrip = wave & 1;
    int nstrip = wave >> 1;
    int lm   = lane & 31;
    int half = lane >> 5;

    int m0 = blockIdx.x * 64 + mstrip * 32;
    int m  = m0 + lm;
    int mc = (m < N_NODES) ? m : (N_NODES - 1);   // clamp for loads; stores guarded
    int n0 = nstrip * 64;

    const float*    arow  = x  + (size_t)mc * 512 + half * 8;
    const _Float16* brow0 = wh + (size_t)(n0 + 2 * lm) * 512 + half * 8;
    const _Float16* brow1 = brow0 + 512;

    f32x16 acc0, acc1;
#pragma unroll
    for (int i = 0; i < 16; ++i) { acc0[i] = 0.f; acc1[i] = 0.f; }

#pragma unroll 4
    for (int k0 = 0; k0 < 512; k0 += 16) {
        float4 a0 = *(const float4*)(arow + k0);
        float4 a1 = *(const float4*)(arow + k0 + 4);
        f16x8 av;
        av[0] = (_Float16)a0.x; av[1] = (_Float16)a0.y; av[2] = (_Float16)a0.z; av[3] = (_Float16)a0.w;
        av[4] = (_Float16)a1.x; av[5] = (_Float16)a1.y; av[6] = (_Float16)a1.z; av[7] = (_Float16)a1.w;
        f16x8 b0 = *(const f16x8*)(brow0 + k0);
        f16x8 b1 = *(const f16x8*)(brow1 + k0);
        acc0 = __builtin_amdgcn_mfma_f32_32x32x16_f16(av, b0, acc0, 0, 0, 0);
        acc1 = __builtin_amdgcn_mfma_f32_32x32x16_f16(av, b1, acc1, 0, 0, 0);
    }

    // C layout: col=lane&31 -> logical n = n0+2*lm (acc0) / n0+2*lm+1 (acc1); row=(reg&3)+8*(reg>>2)+4*half
    float bs0 = bias[n0 + 2 * lm];
    float bs1 = bias[n0 + 2 * lm + 1];
#pragma unroll
    for (int reg = 0; reg < 16; ++reg) {
        int row = (reg & 3) + 8 * (reg >> 2) + 4 * half;
        int gm = m0 + row;
        if (gm < N_NODES) {
            float v0 = fmaxf(acc0[reg] + bs0, 0.f);
            float v1 = fmaxf(acc1[reg] + bs1, 0.f);
            hb[(size_t)gm * 64 + (n0 >> 1) + lm] = __floats2half2_rn(v0, v1);
        }
    }
}

// ---------------- per-node gate dots for layer 0 (from fp16 h) ----------------
__global__ __launch_bounds__(256) void k_dot(const __half2* __restrict__ hb, const float* __restrict__ gw,
                                             const float* __restrict__ gb, const float* __restrict__ nd,
                                             float2* __restrict__ dn, float* __restrict__ dcb) {
    int node = blockIdx.x * 4 + (threadIdx.x >> 6);
    int lane = threadIdx.x & 63;
    float2 wr = ((const float2*)gw)[lane];
    float2 wc = ((const float2*)(gw + 128))[lane];
    float2 hc = __half22float2(hb[(size_t)node * 64 + lane]);
    float a = hc.x * wr.x + hc.y * wr.y;
    float b = hc.x * wc.x + hc.y * wc.y;
#pragma unroll
    for (int off = 32; off >= 1; off >>= 1) {
        a += __shfl_xor(a, off, 64);
        b += __shfl_xor(b, off, 64);
    }
    if (lane == 0) {
        dn[node]  = make_float2(a, nd[node]);
        dcb[node] = b + gb[0];
    }
}

// ---------------- shared prop core: returns new h (fp32) for (node, lane) ----------------
__device__ __forceinline__ float2 prop_core(const __half2* __restrict__ hb, const __half2* __restrict__ raw,
                                            const int* __restrict__ colptr, const int* __restrict__ csr,
                                            const float2* __restrict__ dn, const float* __restrict__ dcb,
                                            const float* __restrict__ nd, int node, int lane) {
    float dc  = dcb[node];
    float ndc = nd[node];
    float acc0 = 0.f, acc1 = 0.f;
    int beg = colptr[node], end = colptr[node + 1];
    for (int base = beg; base < end; base += 64) {
        int e = base + lane;
        int  rr = 0;
        float wv = 0.f;
        if (e < end) {
            rr = csr[e];
            float2 v = dn[rr];
            float xx = v.x + dc;
            float t = __expf(2.0f * xx);          // saturates to inf / 0, no NaN below
            float g = 1.0f - 2.0f / (t + 1.0f);   // == tanh(xx)
            wv = g * v.y * ndc;
        }
        int m = end - base; if (m > 64) m = 64;
#pragma unroll 8
        for (int j = 0; j < m; ++j) {
            int   r = __shfl(rr, j, 64);
            float w = __shfl(wv, j, 64);
            float2 hf = __half22float2(hb[(size_t)r * 64 + lane]);
            acc0 = fmaf(w, hf.x, acc0);
            acc1 = fmaf(w, hf.y, acc1);
        }
    }
    float2 rw = __half22float2(raw[(size_t)node * 64 + lane]);
    float2 o;
    o.x = fmaf(EPS_C, rw.x, acc0);
    o.y = fmaf(EPS_C, rw.y, acc1);
    return o;
}

// ---------------- prop layer 1: write hb1 + fused gate dots for layer 2 ----------------
__global__ __launch_bounds__(256) void k_prop1(const __half2* __restrict__ hb, const __half2* __restrict__ raw,
                                               const int* __restrict__ colptr, const int* __restrict__ csr,
                                               const float2* __restrict__ dn, const float* __restrict__ dcb,
                                               const float* __restrict__ nd,
                                               const float* __restrict__ gw, const float* __restrict__ gb,
                                               __half2* __restrict__ hbn,
                                               float2* __restrict__ dn2, float* __restrict__ dcb2) {
    int node = blockIdx.x * 4 + (threadIdx.x >> 6);
    int lane = threadIdx.x & 63;
    float2 o = prop_core(hb, raw, colptr, csr, dn, dcb, nd, node, lane);
    hbn[(size_t)node * 64 + lane] = __floats2half2_rn(o.x, o.y);
    // fused dots for layer 2 (gw row 1)
    float2 wr = ((const float2*)(gw + 256))[lane];
    float2 wc = ((const float2*)(gw + 256 + 128))[lane];
    float a = o.x * wr.x + o.y * wr.y;
    float b = o.x * wc.x + o.y * wc.y;
#pragma unroll
    for (int off = 32; off >= 1; off >>= 1) {
        a += __shfl_xor(a, off, 64);
        b += __shfl_xor(b, off, 64);
    }
    if (lane == 0) {
        dn2[node]  = make_float2(a, nd[node]);
        dcb2[node] = b + gb[1];
    }
}

// ---------------- prop layer 2 + fused output GEMM + log_softmax ----------------
__global__ __launch_bounds__(256) void k_prop2(const __half2* __restrict__ hb, const __half2* __restrict__ raw,
                                               const int* __restrict__ colptr, const int* __restrict__ csr,
                                               const float2* __restrict__ dn, const float* __restrict__ dcb,
                                               const float* __restrict__ nd,
                                               const float* __restrict__ w2, const float* __restrict__ b2,
                                               float* __restrict__ out) {
    __shared__ float w2t[128][40];
    __shared__ float hs[4][128];
    int wid  = threadIdx.x >> 6;
    int lane = threadIdx.x & 63;
    int node = blockIdx.x * 4 + wid;

    for (int idx = threadIdx.x; idx < 40 * 128; idx += 256) {
        int j = idx >> 7;
        int i = idx & 127;
        w2t[i][j] = w2[idx];
    }
    float2 o = prop_core(hb, raw, colptr, csr, dn, dcb, nd, node, lane);
    hs[wid][2 * lane]     = o.x;
    hs[wid][2 * lane + 1] = o.y;
    __syncthreads();

    int j = lane;
    float logit = -INFINITY;
    if (j < 40) {
        float a = 0.f;
#pragma unroll 8
        for (int i = 0; i < 128; ++i) a = fmaf(hs[wid][i], w2t[i][j], a);
        logit = a + b2[j];
    }
    float mx = logit;
#pragma unroll
    for (int off = 32; off >= 1; off >>= 1) mx = fmaxf(mx, __shfl_xor(mx, off, 64));
    float ex = (j < 40) ? expf(logit - mx) : 0.f;
    float sum = ex;
#pragma unroll
    for (int off = 32; off >= 1; off >>= 1) sum += __shfl_xor(sum, off, 64);
    float ls = logf(sum);
    if (j < 40) out[(size_t)node * 40 + j] = logit - mx - ls;
}

extern "C" void kernel_launch(void* const* d_in, const int* in_sizes, int n_in,
                              void* d_out, int out_size, void* d_ws, size_t ws_size,
                              hipStream_t stream) {
    const float* x   = (const float*)d_in[0];
    const int*   ei  = (const int*)  d_in[1];
    const float* t1w = (const float*)d_in[2];
    const float* t1b = (const float*)d_in[3];
    const float* gw  = (const float*)d_in[4];
    const float* gb  = (const float*)d_in[5];
    const float* w2  = (const float*)d_in[6];
    const float* b2  = (const float*)d_in[7];
    float* out = (float*)d_out;

    char* p = (char*)d_ws;
    int*    colptr = (int*)p;    p += (size_t)(N_NODES + 64) * 4;
    float*  nd     = (float*)p;  p += (size_t)N_NODES * 4;
    int*    cnt    = (int*)p;    p += (size_t)N_NODES * 4;
    float*  dcb    = (float*)p;  p += (size_t)N_NODES * 4;
    float*  dcb2   = (float*)p;  p += (size_t)N_NODES * 4;
    float2* dn     = (float2*)p; p += (size_t)N_NODES * 8;
    float2* dn2    = (float2*)p; p += (size_t)N_NODES * 8;
    int*    csr    = (int*)p;    p += (size_t)N_EDGES * 4;
    _Float16* wh   = (_Float16*)p; p += (size_t)HIDDEN * 512 * 2;
    // hb0 region overlaps the transient hist buffers (dead before k_gemm1 writes hb0)
    char* q = p;
    unsigned int*   part   = (unsigned int*)q;                                        // 6.4 MB
    unsigned short* cntpre = (unsigned short*)(q + (size_t)2 * NCHUNK * NWORDS * 4);  // 6.4 MB
    __half2* hb0 = (__half2*)p; p += (size_t)N_NODES * 64 * 4;   // 12.8 MB
    __half2* hb1 = (__half2*)p; p += (size_t)N_NODES * 64 * 4;   // 12.8 MB

    // ---- graph preprocessing (zero global atomics) ----
    k_hist<<<128, 256, 0, stream>>>(ei, part);
    k_reduce<<<RBLOCKS + 64, 256, 0, stream>>>(part, nd, cnt, cntpre,
                                               (const float4*)t1w, (__half2*)wh);
    k_scan<<<1, 1024, 0, stream>>>(cnt, colptr);
    k_scatter2<<<NCHUNK, 256, 0, stream>>>(ei, colptr, cntpre, csr);

    // ---- dense pipeline (all h in fp16) ----
    k_gemm1<<<(N_NODES + 63) / 64, 256, 0, stream>>>(x, wh, t1b, hb0);
    k_dot  <<<N_NODES / 4, 256, 0, stream>>>(hb0, gw, gb, nd, dn, dcb);
    k_prop1<<<N_NODES / 4, 256, 0, stream>>>(hb0, hb0, colptr, csr, dn, dcb, nd,
                                             gw, gb, hb1, dn2, dcb2);
    k_prop2<<<N_NODES / 4, 256, 0, stream>>>(hb1, hb0, colptr, csr, dn2, dcb2, nd,
                                             w2, b2, out);
}